// Round 1
// baseline (426.227 us; speedup 1.0000x reference)
//
#include <hip/hip_runtime.h>

// GraphAttention: e[b,n,k,o] = T[b,n,o] + U[b,idx[b,n,k],o]  (exact factorization
// of einsum('bnkc,oc', [centre-nb, nb], W)); BN affine folded into T,U.
// Then leaky(0.2) -> softmax over k -> dot with feature[b,o,n,:] -> out[b,o,n].

constexpr int B_ = 8, C_ = 64, N_ = 4096, K_ = 32, O_ = 64;

// ---------------- Kernel A: T'[b,n,o], U'[b,n,o] precompute ----------------
// block = 256 threads, covers one b and 64 consecutive n rows, all 64 o.
// Register tile 4n x 4o per thread; operands staged transposed in LDS so the
// inner loop is 3x ds_read_b128 + 32 fma.
__global__ __launch_bounds__(256) void gat_pre(
    const float* __restrict__ x, const float* __restrict__ W,
    const float* __restrict__ gamma, const float* __restrict__ beta,
    const float* __restrict__ bn_mean, const float* __restrict__ bn_var,
    float* __restrict__ T, float* __restrict__ U)
{
    __shared__ float xsT[64][68];   // [c][n_local], stride 68 keeps 16B align + no conflicts
    __shared__ float wt1[64][68];   // [c][o] = W1[o][c]
    __shared__ float wtd[64][68];   // [c][o] = W2[o][c]-W1[o][c]

    const int blk = blockIdx.x;
    const int b = blk & 7;                 // XCD-pinned batch
    const int n_base = (blk >> 3) << 6;
    const int t = threadIdx.x;

    // stage x tile (64n x 64c, contiguous 16KB) transposed into LDS
    const float* xb = x + ((size_t)b * N_ + n_base) * C_;
    #pragma unroll
    for (int r = 0; r < 4; ++r) {
        const int e0 = r * 1024 + t * 4;
        const float4 v = *reinterpret_cast<const float4*>(xb + e0);
        xsT[(e0 + 0) & 63][(e0 + 0) >> 6] = v.x;
        xsT[(e0 + 1) & 63][(e0 + 1) >> 6] = v.y;
        xsT[(e0 + 2) & 63][(e0 + 2) >> 6] = v.z;
        xsT[(e0 + 3) & 63][(e0 + 3) >> 6] = v.w;
    }
    // stage W transposed (L2-hot after first block)
    #pragma unroll
    for (int i = 0; i < 16; ++i) {
        const int idx = i * 256 + t;
        const int o = idx >> 6, c = idx & 63;
        const float w1 = W[o * 128 + c];
        const float w2 = W[o * 128 + 64 + c];
        wt1[c][o] = w1;
        wtd[c][o] = w2 - w1;
    }
    __syncthreads();

    const int o0 = (t & 15) * 4;
    const int n0 = (t >> 4) * 4;
    float accT[4][4] = {};
    float accU[4][4] = {};
    #pragma unroll 4
    for (int c = 0; c < 64; ++c) {
        const float4 xn = *reinterpret_cast<const float4*>(&xsT[c][n0]);
        const float4 w1 = *reinterpret_cast<const float4*>(&wt1[c][o0]);
        const float4 wd = *reinterpret_cast<const float4*>(&wtd[c][o0]);
        const float xa[4] = {xn.x, xn.y, xn.z, xn.w};
        const float wa[4] = {w1.x, w1.y, w1.z, w1.w};
        const float da[4] = {wd.x, wd.y, wd.z, wd.w};
        #pragma unroll
        for (int i = 0; i < 4; ++i)
            #pragma unroll
            for (int j = 0; j < 4; ++j) {
                accT[i][j] = fmaf(xa[i], wa[j], accT[i][j]);
                accU[i][j] = fmaf(xa[i], da[j], accU[i][j]);
            }
    }

    // fold BN affine: T' = T*inv + bias, U' = U*inv   (e = T'+U' exactly)
    float inv[4], bias[4];
    #pragma unroll
    for (int j = 0; j < 4; ++j) {
        const int o = o0 + j;
        const float iv = gamma[o] * rsqrtf(bn_var[o] + 1e-5f);
        inv[j] = iv;
        bias[j] = beta[o] - bn_mean[o] * iv;
    }
    #pragma unroll
    for (int i = 0; i < 4; ++i) {
        const int n = n_base + n0 + i;
        float tvv[4], uvv[4];
        #pragma unroll
        for (int j = 0; j < 4; ++j) {
            tvv[j] = fmaf(accT[i][j], inv[j], bias[j]);
            uvv[j] = accU[i][j] * inv[j];
        }
        float* tp = T + ((size_t)b * N_ + n) * O_ + o0;
        float* up = U + ((size_t)b * N_ + n) * O_ + o0;
        *reinterpret_cast<float4*>(tp) = make_float4(tvv[0], tvv[1], tvv[2], tvv[3]);
        *reinterpret_cast<float4*>(up) = make_float4(uvv[0], uvv[1], uvv[2], uvv[3]);
    }
}

// ---------------- Kernel B: gather + softmax + weighted feature sum ----------------
// block = 256 (4 waves), covers (b, 16 consecutive n). Wave w handles n = base+4w+r,
// lane = o. U gathers are 256B coalesced, L2-resident (batch pinned to XCD).
__global__ __launch_bounds__(256) void gat_main(
    const int* __restrict__ gi, const float* __restrict__ feat,
    const float* __restrict__ T, const float* __restrict__ U,
    float* __restrict__ out)
{
    __shared__ float tmp[64][17];
    const int blk = blockIdx.x;
    const int b = blk & 7;                 // XCD-pinned batch
    const int n_base = (blk >> 3) * 16;
    const int t = threadIdx.x;
    const int w = t >> 6;
    const int lane = t & 63;               // = o

    for (int r = 0; r < 4; ++r) {
        const int n = n_base + w * 4 + r;
        int vi = 0;
        if (lane < 32) vi = gi[((size_t)b * N_ + n) * K_ + lane];
        const float tv = T[((size_t)b * N_ + n) * O_ + lane];

        float e[32];
        float emax = -3.0e38f;
        #pragma unroll
        for (int k = 0; k < 32; ++k) {
            const int m = __shfl(vi, k, 64);
            const float u = U[((size_t)b * N_ + m) * O_ + lane];
            float ev = tv + u;
            ev = fmaxf(ev, 0.2f * ev);     // leaky relu, slope 0.2
            e[k] = ev;
            emax = fmaxf(emax, ev);
        }

        const float* fp = feat + (((size_t)b * O_ + lane) * N_ + n) * K_;
        float num = 0.f, den = 0.f;
        #pragma unroll
        for (int k4 = 0; k4 < 8; ++k4) {
            const float4 f = *reinterpret_cast<const float4*>(fp + k4 * 4);
            const float p0 = __expf(e[k4 * 4 + 0] - emax);
            const float p1 = __expf(e[k4 * 4 + 1] - emax);
            const float p2 = __expf(e[k4 * 4 + 2] - emax);
            const float p3 = __expf(e[k4 * 4 + 3] - emax);
            num = fmaf(p0, f.x, num); den += p0;
            num = fmaf(p1, f.y, num); den += p1;
            num = fmaf(p2, f.z, num); den += p2;
            num = fmaf(p3, f.w, num); den += p3;
        }
        tmp[lane][w * 4 + r] = num / den;
    }
    __syncthreads();

    // coalesced transpose-write: 16 consecutive n per o = one 64B line
    #pragma unroll
    for (int r = 0; r < 4; ++r) {
        const int o = r * 16 + (t >> 4);
        const int ns = t & 15;
        out[((size_t)b * O_ + o) * N_ + n_base + ns] = tmp[o][ns];
    }
}

extern "C" void kernel_launch(void* const* d_in, const int* in_sizes, int n_in,
                              void* d_out, int out_size, void* d_ws, size_t ws_size,
                              hipStream_t stream) {
    const int*   gi      = (const int*)d_in[0];
    const float* x       = (const float*)d_in[1];
    const float* feat    = (const float*)d_in[2];
    const float* W       = (const float*)d_in[3];
    const float* gamma   = (const float*)d_in[4];
    const float* beta    = (const float*)d_in[5];
    const float* bn_mean = (const float*)d_in[6];
    const float* bn_var  = (const float*)d_in[7];
    float* out = (float*)d_out;

    float* T = (float*)d_ws;                          // B*N*O floats = 8MB
    float* U = T + (size_t)B_ * N_ * O_;              // + 8MB (ws re-poisoned each
                                                      // launch; fully rewritten here)
    gat_pre<<<dim3(B_ * (N_ / 64)), dim3(256), 0, stream>>>(
        x, W, gamma, beta, bn_mean, bn_var, T, U);
    gat_main<<<dim3(B_ * (N_ / 16)), dim3(256), 0, stream>>>(
        gi, feat, T, U, out);
}